// Round 1
// baseline (611.893 us; speedup 1.0000x reference)
//
#include <hip/hip_runtime.h>

#define NN 100000
#define NE 1600000

// ---- CSR build -------------------------------------------------------------

__global__ void k_deg(const int* __restrict__ dst, int* __restrict__ deg) {
    int e = blockIdx.x * blockDim.x + threadIdx.x;
    if (e < NE) atomicAdd(&deg[dst[e]], 1);
}

__global__ __launch_bounds__(1024) void k_scan(const int* __restrict__ deg,
                                               int* __restrict__ offsets) {
    __shared__ int sums[1024];
    const int t = threadIdx.x;
    const int chunk = (NN + 1023) / 1024;   // 98
    int lo = t * chunk;
    int hi = min(lo + chunk, NN);
    int s = 0;
    for (int i = lo; i < hi; ++i) s += deg[i];
    sums[t] = s;
    __syncthreads();
    // Hillis-Steele inclusive scan over 1024 partials
    for (int off = 1; off < 1024; off <<= 1) {
        int v = (t >= off) ? sums[t - off] : 0;
        __syncthreads();
        sums[t] += v;
        __syncthreads();
    }
    int run = (t == 0) ? 0 : sums[t - 1];
    for (int i = lo; i < hi; ++i) { offsets[i] = run; run += deg[i]; }
    if (t == 1023) offsets[NN] = sums[1023];
}

__global__ void k_prep(const int* __restrict__ offsets, const int* __restrict__ deg,
                       int* __restrict__ cursor, float* __restrict__ inv) {
    int i = blockIdx.x * blockDim.x + threadIdx.x;
    if (i < NN) {
        cursor[i] = offsets[i];
        inv[i] = 1.0f / fmaxf((float)deg[i], 1.0f);
    }
}

__global__ void k_fill(const int* __restrict__ src, const int* __restrict__ dst,
                       int* __restrict__ cursor, int* __restrict__ csr) {
    int e = blockIdx.x * blockDim.x + threadIdx.x;
    if (e < NE) {
        int d = dst[e];
        int p = atomicAdd(&cursor[d], 1);
        csr[p] = src[e];
    }
}

// ---- Aggregation: wave per node, lane = feature ----------------------------
// A[n][0:64]   = mean-aggregated neighbor features
// A[n][64:128] = the node's own features (self path input)
__global__ void k_agg(const float* __restrict__ feat, const int* __restrict__ offsets,
                      const int* __restrict__ csr, const float* __restrict__ inv,
                      float* __restrict__ A) {
    int wid = (blockIdx.x * blockDim.x + threadIdx.x) >> 6;   // node index
    int f = threadIdx.x & 63;
    if (wid >= NN) return;
    int beg = offsets[wid];
    int end = offsets[wid + 1];
    float acc = 0.f;
    int j = beg;
    for (; j + 4 <= end; j += 4) {
        int s0 = csr[j], s1 = csr[j + 1], s2 = csr[j + 2], s3 = csr[j + 3];
        float v0 = feat[(size_t)s0 * 64 + f];
        float v1 = feat[(size_t)s1 * 64 + f];
        float v2 = feat[(size_t)s2 * 64 + f];
        float v3 = feat[(size_t)s3 * 64 + f];
        acc += v0; acc += v1; acc += v2; acc += v3;
    }
    for (; j < end; ++j) acc += feat[(size_t)csr[j] * 64 + f];
    A[(size_t)wid * 128 + f] = acc * inv[wid];
    A[(size_t)wid * 128 + 64 + f] = feat[(size_t)wid * 64 + f];
}

// ---- Node transform: C[n][fo] = sum_k A[n][k] * Wcat[fo][k] + bias[fo] -----
// Wcat = [Wl | Wr] (K = 128). Tiled 64 nodes x 64 fout, f32 VALU (no fp32 MFMA).
__global__ __launch_bounds__(256) void k_gemm(const float* __restrict__ A,
                                              const float* __restrict__ Wl,
                                              const float* __restrict__ Wr,
                                              const float* __restrict__ bias,
                                              float* __restrict__ C) {
    __shared__ float As[64][132];    // +4 pad: A-read aliasing <= 2-way (free)
    __shared__ float Ws[128][64];    // transposed weights: Ws[k][fo]
    const int t = threadIdx.x;
    const int n0 = blockIdx.x * 64;

    // stage transposed weights (once per block)
    for (int e = t; e < 4096; e += 256) {
        int fo = e >> 6, k = e & 63;
        Ws[k][fo] = Wl[e];
        Ws[64 + k][fo] = Wr[e];
    }
    // stage A tile: 64 rows x 128 cols, float4
    for (int v = t; v < 2048; v += 256) {
        int row = v >> 5;
        int col = (v & 31) << 2;
        int n = n0 + row;
        float4 val = (n < NN) ? *(const float4*)(A + (size_t)n * 128 + col)
                              : make_float4(0.f, 0.f, 0.f, 0.f);
        *(float4*)(&As[row][col]) = val;
    }
    __syncthreads();

    const int tx = t & 15;           // fout group: fo = tx*4 .. +3
    const int ty = t >> 4;           // node group: n  = ty*4 .. +3
    float acc[4][4] = {};
    #pragma unroll 2
    for (int k = 0; k < 128; k += 4) {
        float a[4][4], w[4][4];
        #pragma unroll
        for (int i = 0; i < 4; ++i)
            *(float4*)a[i] = *(const float4*)(&As[ty * 4 + i][k]);
        #pragma unroll
        for (int kk = 0; kk < 4; ++kk)
            *(float4*)w[kk] = *(const float4*)(&Ws[k + kk][tx * 4]);
        #pragma unroll
        for (int i = 0; i < 4; ++i)
            #pragma unroll
            for (int kk = 0; kk < 4; ++kk)
                #pragma unroll
                for (int j = 0; j < 4; ++j)
                    acc[i][j] = fmaf(a[i][kk], w[kk][j], acc[i][j]);
    }

    float4 bv = *(const float4*)(bias + tx * 4);
    #pragma unroll
    for (int i = 0; i < 4; ++i) {
        int n = n0 + ty * 4 + i;
        if (n < NN) {
            float4 o;
            o.x = acc[i][0] + bv.x;
            o.y = acc[i][1] + bv.y;
            o.z = acc[i][2] + bv.z;
            o.w = acc[i][3] + bv.w;
            *(float4*)(C + (size_t)n * 64 + tx * 4) = o;
        }
    }
}

// ---- host ------------------------------------------------------------------

extern "C" void kernel_launch(void* const* d_in, const int* in_sizes, int n_in,
                              void* d_out, int out_size, void* d_ws, size_t ws_size,
                              hipStream_t stream) {
    const float* x   = (const float*)d_in[0];
    const int*   ei  = (const int*)d_in[1];     // [2][NE], int32
    const int*   src = ei;
    const int*   dst = ei + NE;
    const float* Wl1 = (const float*)d_in[2];
    const float* b1  = (const float*)d_in[3];
    const float* Wr1 = (const float*)d_in[4];
    const float* Wl2 = (const float*)d_in[5];
    const float* b2  = (const float*)d_in[6];
    const float* Wr2 = (const float*)d_in[7];
    float* out = (float*)d_out;

    char* ws = (char*)d_ws;
    size_t off = 0;
    auto alloc = [&](size_t bytes) {
        void* p = ws + off;
        off = (off + bytes + 255) & ~(size_t)255;
        return p;
    };
    float* A       = (float*)alloc(sizeof(float) * (size_t)NN * 128); // 51.2 MB
    int*   csr     = (int*)alloc(sizeof(int) * NE);                   // 6.4 MB
    int*   offsets = (int*)alloc(sizeof(int) * (NN + 1));
    int*   cursor  = (int*)alloc(sizeof(int) * NN);
    int*   deg     = (int*)alloc(sizeof(int) * NN);
    float* inv     = (float*)alloc(sizeof(float) * NN);

    hipMemsetAsync(deg, 0, sizeof(int) * NN, stream);

    // CSR build (reused by both layers)
    k_deg <<<(NE + 255) / 256, 256, 0, stream>>>(dst, deg);
    k_scan<<<1, 1024, 0, stream>>>(deg, offsets);
    k_prep<<<(NN + 255) / 256, 256, 0, stream>>>(offsets, deg, cursor, inv);
    k_fill<<<(NE + 255) / 256, 256, 0, stream>>>(src, dst, cursor, csr);

    // layer 1: A = [mean-agg(x) | x]; out = A @ [Wl1|Wr1]^T + b1
    k_agg <<<((size_t)NN * 64 + 255) / 256, 256, 0, stream>>>(x, offsets, csr, inv, A);
    k_gemm<<<(NN + 63) / 64, 256, 0, stream>>>(A, Wl1, Wr1, b1, out);

    // layer 2: A = [mean-agg(h1) | h1]; out = A @ [Wl2|Wr2]^T + b2
    k_agg <<<((size_t)NN * 64 + 255) / 256, 256, 0, stream>>>(out, offsets, csr, inv, A);
    k_gemm<<<(NN + 63) / 64, 256, 0, stream>>>(A, Wl2, Wr2, b2, out);
}

// Round 2
// 460.268 us; speedup vs baseline: 1.3294x; 1.3294x over previous
//
#include <hip/hip_runtime.h>

#define NN 100000
#define NE 1600000
#define SCAN_BLKS 98          // ceil(NN / 1024), each block covers 1024 nodes

// ---- CSR build -------------------------------------------------------------

__global__ void k_deg(const int* __restrict__ dst, int* __restrict__ deg) {
    int e = blockIdx.x * blockDim.x + threadIdx.x;
    if (e < NE) atomicAdd(&deg[dst[e]], 1);
}

// phase 1: per-block sum of 1024 deg values
__global__ __launch_bounds__(256) void k_bsum(const int* __restrict__ deg,
                                              int* __restrict__ bsum) {
    const int t = threadIdx.x;
    const int base = blockIdx.x * 1024 + t * 4;
    int s = 0;
    #pragma unroll
    for (int k = 0; k < 4; ++k) {
        int i = base + k;
        if (i < NN) s += deg[i];
    }
    #pragma unroll
    for (int off = 32; off > 0; off >>= 1) s += __shfl_down(s, off, 64);
    __shared__ int ws[4];
    if ((t & 63) == 0) ws[t >> 6] = s;
    __syncthreads();
    if (t == 0) bsum[blockIdx.x] = ws[0] + ws[1] + ws[2] + ws[3];
}

// phase 2: one tiny block scans the 98 block sums -> exclusive block offsets
__global__ __launch_bounds__(128) void k_bscan(const int* __restrict__ bsum,
                                               int* __restrict__ boff) {
    __shared__ int s[128];
    const int t = threadIdx.x;
    int v = (t < SCAN_BLKS) ? bsum[t] : 0;
    s[t] = v;
    __syncthreads();
    #pragma unroll
    for (int off = 1; off < 128; off <<= 1) {
        int u = (t >= off) ? s[t - off] : 0;
        __syncthreads();
        s[t] += u;
        __syncthreads();
    }
    if (t < SCAN_BLKS) boff[t] = s[t] - v;   // exclusive
}

// phase 3: per-block exclusive scan + write offsets, cursor, inv
__global__ __launch_bounds__(256) void k_scan3(const int* __restrict__ deg,
                                               const int* __restrict__ boff,
                                               int* __restrict__ offsets,
                                               int* __restrict__ cursor,
                                               float* __restrict__ inv) {
    __shared__ int s[256];
    const int t = threadIdx.x;
    const int base = blockIdx.x * 1024 + t * 4;
    int v[4];
    int tot = 0;
    #pragma unroll
    for (int k = 0; k < 4; ++k) {
        int i = base + k;
        v[k] = (i < NN) ? deg[i] : 0;
        tot += v[k];
    }
    s[t] = tot;
    __syncthreads();
    #pragma unroll
    for (int off = 1; off < 256; off <<= 1) {
        int u = (t >= off) ? s[t - off] : 0;
        __syncthreads();
        s[t] += u;
        __syncthreads();
    }
    int run = boff[blockIdx.x] + s[t] - tot;   // exclusive prefix for this thread
    #pragma unroll
    for (int k = 0; k < 4; ++k) {
        int i = base + k;
        if (i < NN) {
            offsets[i] = run;
            cursor[i] = run;
            inv[i] = 1.0f / fmaxf((float)v[k], 1.0f);
            run += v[k];
            if (i == NN - 1) offsets[NN] = run;
        }
    }
}

__global__ void k_fill(const int* __restrict__ src, const int* __restrict__ dst,
                       int* __restrict__ cursor, int* __restrict__ csr) {
    int e = blockIdx.x * blockDim.x + threadIdx.x;
    if (e < NE) {
        int d = dst[e];
        int p = atomicAdd(&cursor[d], 1);
        csr[p] = src[e];
    }
}

// ---- Aggregation: wave per node, lane = feature ----------------------------
// A[n][0:64]   = mean-aggregated neighbor features
// A[n][64:128] = the node's own features (self path input)
__global__ void k_agg(const float* __restrict__ feat, const int* __restrict__ offsets,
                      const int* __restrict__ csr, const float* __restrict__ inv,
                      float* __restrict__ A) {
    int wid = (blockIdx.x * blockDim.x + threadIdx.x) >> 6;   // node index
    int f = threadIdx.x & 63;
    if (wid >= NN) return;
    int beg = offsets[wid];
    int end = offsets[wid + 1];
    float acc = 0.f;
    int j = beg;
    for (; j + 4 <= end; j += 4) {
        int s0 = csr[j], s1 = csr[j + 1], s2 = csr[j + 2], s3 = csr[j + 3];
        float v0 = feat[(size_t)s0 * 64 + f];
        float v1 = feat[(size_t)s1 * 64 + f];
        float v2 = feat[(size_t)s2 * 64 + f];
        float v3 = feat[(size_t)s3 * 64 + f];
        acc += v0; acc += v1; acc += v2; acc += v3;
    }
    for (; j < end; ++j) acc += feat[(size_t)csr[j] * 64 + f];
    A[(size_t)wid * 128 + f] = acc * inv[wid];
    A[(size_t)wid * 128 + 64 + f] = feat[(size_t)wid * 64 + f];
}

// ---- Node transform: C[n][fo] = sum_k A[n][k] * Wcat[fo][k] + bias[fo] -----
// Wcat = [Wl | Wr] (K = 128). Tiled 64 nodes x 64 fout, f32 VALU (no fp32 MFMA).
__global__ __launch_bounds__(256) void k_gemm(const float* __restrict__ A,
                                              const float* __restrict__ Wl,
                                              const float* __restrict__ Wr,
                                              const float* __restrict__ bias,
                                              float* __restrict__ C) {
    __shared__ float As[64][132];    // +4 pad: A-read aliasing <= 2-way (free)
    __shared__ float Ws[128][64];    // transposed weights: Ws[k][fo]
    const int t = threadIdx.x;
    const int n0 = blockIdx.x * 64;

    // stage transposed weights (once per block)
    for (int e = t; e < 4096; e += 256) {
        int fo = e >> 6, k = e & 63;
        Ws[k][fo] = Wl[e];
        Ws[64 + k][fo] = Wr[e];
    }
    // stage A tile: 64 rows x 128 cols, float4
    for (int v = t; v < 2048; v += 256) {
        int row = v >> 5;
        int col = (v & 31) << 2;
        int n = n0 + row;
        float4 val = (n < NN) ? *(const float4*)(A + (size_t)n * 128 + col)
                              : make_float4(0.f, 0.f, 0.f, 0.f);
        *(float4*)(&As[row][col]) = val;
    }
    __syncthreads();

    const int tx = t & 15;           // fout group: fo = tx*4 .. +3
    const int ty = t >> 4;           // node group: n  = ty*4 .. +3
    float acc[4][4] = {};
    #pragma unroll 2
    for (int k = 0; k < 128; k += 4) {
        float a[4][4], w[4][4];
        #pragma unroll
        for (int i = 0; i < 4; ++i)
            *(float4*)a[i] = *(const float4*)(&As[ty * 4 + i][k]);
        #pragma unroll
        for (int kk = 0; kk < 4; ++kk)
            *(float4*)w[kk] = *(const float4*)(&Ws[k + kk][tx * 4]);
        #pragma unroll
        for (int i = 0; i < 4; ++i)
            #pragma unroll
            for (int kk = 0; kk < 4; ++kk)
                #pragma unroll
                for (int j = 0; j < 4; ++j)
                    acc[i][j] = fmaf(a[i][kk], w[kk][j], acc[i][j]);
    }

    float4 bv = *(const float4*)(bias + tx * 4);
    #pragma unroll
    for (int i = 0; i < 4; ++i) {
        int n = n0 + ty * 4 + i;
        if (n < NN) {
            float4 o;
            o.x = acc[i][0] + bv.x;
            o.y = acc[i][1] + bv.y;
            o.z = acc[i][2] + bv.z;
            o.w = acc[i][3] + bv.w;
            *(float4*)(C + (size_t)n * 64 + tx * 4) = o;
        }
    }
}

// ---- host ------------------------------------------------------------------

extern "C" void kernel_launch(void* const* d_in, const int* in_sizes, int n_in,
                              void* d_out, int out_size, void* d_ws, size_t ws_size,
                              hipStream_t stream) {
    const float* x   = (const float*)d_in[0];
    const int*   ei  = (const int*)d_in[1];     // [2][NE], int32
    const int*   src = ei;
    const int*   dst = ei + NE;
    const float* Wl1 = (const float*)d_in[2];
    const float* b1  = (const float*)d_in[3];
    const float* Wr1 = (const float*)d_in[4];
    const float* Wl2 = (const float*)d_in[5];
    const float* b2  = (const float*)d_in[6];
    const float* Wr2 = (const float*)d_in[7];
    float* out = (float*)d_out;

    char* ws = (char*)d_ws;
    size_t off = 0;
    auto alloc = [&](size_t bytes) {
        void* p = ws + off;
        off = (off + bytes + 255) & ~(size_t)255;
        return p;
    };
    float* A       = (float*)alloc(sizeof(float) * (size_t)NN * 128); // 51.2 MB
    int*   csr     = (int*)alloc(sizeof(int) * NE);                   // 6.4 MB
    int*   offsets = (int*)alloc(sizeof(int) * (NN + 1));
    int*   cursor  = (int*)alloc(sizeof(int) * NN);
    int*   deg     = (int*)alloc(sizeof(int) * NN);
    float* inv     = (float*)alloc(sizeof(float) * NN);
    int*   bsum    = (int*)alloc(sizeof(int) * SCAN_BLKS);
    int*   boff    = (int*)alloc(sizeof(int) * SCAN_BLKS);

    hipMemsetAsync(deg, 0, sizeof(int) * NN, stream);

    // CSR build (reused by both layers)
    k_deg  <<<(NE + 255) / 256, 256, 0, stream>>>(dst, deg);
    k_bsum <<<SCAN_BLKS, 256, 0, stream>>>(deg, bsum);
    k_bscan<<<1, 128, 0, stream>>>(bsum, boff);
    k_scan3<<<SCAN_BLKS, 256, 0, stream>>>(deg, boff, offsets, cursor, inv);
    k_fill <<<(NE + 255) / 256, 256, 0, stream>>>(src, dst, cursor, csr);

    // layer 1: A = [mean-agg(x) | x]; out = A @ [Wl1|Wr1]^T + b1
    k_agg <<<((size_t)NN * 64 + 255) / 256, 256, 0, stream>>>(x, offsets, csr, inv, A);
    k_gemm<<<(NN + 63) / 64, 256, 0, stream>>>(A, Wl1, Wr1, b1, out);

    // layer 2: A = [mean-agg(h1) | h1]; out = A @ [Wl2|Wr2]^T + b2
    k_agg <<<((size_t)NN * 64 + 255) / 256, 256, 0, stream>>>(out, offsets, csr, inv, A);
    k_gemm<<<(NN + 63) / 64, 256, 0, stream>>>(A, Wl2, Wr2, b2, out);
}

// Round 3
// 301.500 us; speedup vs baseline: 2.0295x; 1.5266x over previous
//
#include <hip/hip_runtime.h>

#define NN 100000
#define NE 1600000
#define NB 196            // dst-range buckets of 512 nodes
#define BCAP 9216         // padded bucket capacity (mean 8192, sd ~90 -> +11 sigma)
#define BIN_CHUNK 8192
#define BIN_BLKS ((NE + BIN_CHUNK - 1) / BIN_CHUNK)   // 196

// ---- bucket cursors init (every launch: deterministic) ---------------------
__global__ void k_init(int* __restrict__ gcur) {
    int t = threadIdx.x;
    if (t < NB) gcur[t] = t * BCAP;
}

// ---- bin edges by dst>>9 into padded bucket regions ------------------------
// packed word = (dst&511)<<17 | src   (src < 2^17, local dst < 2^9)
__global__ __launch_bounds__(256) void k_bin(const int* __restrict__ src,
                                             const int* __restrict__ dst,
                                             int* __restrict__ gcur,
                                             unsigned* __restrict__ binned) {
    __shared__ int hist[NB];
    __shared__ int base[NB];
    __shared__ int lcur[NB];
    const int t = threadIdx.x;
    const int e0 = blockIdx.x * BIN_CHUNK;
    const int n = min(BIN_CHUNK, NE - e0);
    for (int i = t; i < NB; i += 256) { hist[i] = 0; lcur[i] = 0; }
    __syncthreads();
    for (int i = t; i < n; i += 256)
        atomicAdd(&hist[dst[e0 + i] >> 9], 1);
    __syncthreads();
    for (int i = t; i < NB; i += 256) {
        int h = hist[i];
        base[i] = h ? atomicAdd(&gcur[i], h) : 0;   // one global atomic per (block,bucket)
    }
    __syncthreads();
    for (int i = t; i < n; i += 256) {
        int d = dst[e0 + i];
        int s = src[e0 + i];
        int b = d >> 9;
        int p = base[b] + atomicAdd(&lcur[b], 1);   // LDS cursor
        binned[p] = ((unsigned)(d & 511) << 17) | (unsigned)s;
    }
}

// ---- per-bucket CSR finalize: histogram + scan + in-place permute ----------
// After this, binned[] holds src indices grouped by dst; noff[n] = {start,end}.
__global__ __launch_bounds__(256) void k_csr(const int* __restrict__ gcur,
                                             unsigned* __restrict__ binned,
                                             int2* __restrict__ noff,
                                             float* __restrict__ inv) {
    __shared__ unsigned buf[BCAP];      // 36.9 KB
    __shared__ int h[512];
    __shared__ int off[512];
    __shared__ int lcur[512];
    __shared__ int s[256];
    const int b = blockIdx.x;
    const int t = threadIdx.x;
    const int base = b * BCAP;
    const int cnt = min(gcur[b] - base, BCAP);
    for (int i = t; i < 512; i += 256) h[i] = 0;
    __syncthreads();
    for (int i = t; i < cnt; i += 256) {
        unsigned v = binned[base + i];
        buf[i] = v;
        atomicAdd(&h[v >> 17], 1);
    }
    __syncthreads();
    // exclusive scan of 512 counters with 256 threads (2 per thread)
    int a0 = h[2 * t], a1 = h[2 * t + 1];
    s[t] = a0 + a1;
    __syncthreads();
    #pragma unroll
    for (int o = 1; o < 256; o <<= 1) {
        int u = (t >= o) ? s[t - o] : 0;
        __syncthreads();
        s[t] += u;
        __syncthreads();
    }
    int ex = s[t] - (a0 + a1);
    off[2 * t] = ex;         lcur[2 * t] = ex;
    off[2 * t + 1] = ex + a0; lcur[2 * t + 1] = ex + a0;
    __syncthreads();
    // place (reads were all staged to LDS; in-place global permute is safe)
    for (int i = t; i < cnt; i += 256) {
        unsigned v = buf[i];
        int dl = v >> 17;
        int p = atomicAdd(&lcur[dl], 1);
        binned[base + p] = v & 0x1FFFFu;
    }
    // node outputs
    #pragma unroll
    for (int q = 0; q < 2; ++q) {
        int l = 2 * t + q;
        int node = b * 512 + l;
        if (node < NN) {
            int st = base + off[l];
            noff[node] = make_int2(st, st + h[l]);
            inv[node] = 1.0f / fmaxf((float)h[l], 1.0f);
        }
    }
}

// ---- Aggregation: wave per node, lane = feature ----------------------------
__global__ void k_agg(const float* __restrict__ feat, const int2* __restrict__ noff,
                      const unsigned* __restrict__ csr, const float* __restrict__ inv,
                      float* __restrict__ A) {
    int wid = (blockIdx.x * blockDim.x + threadIdx.x) >> 6;   // node index
    int f = threadIdx.x & 63;
    if (wid >= NN) return;
    int2 oe = noff[wid];
    int beg = oe.x, end = oe.y;
    float acc = 0.f;
    int j = beg;
    for (; j + 4 <= end; j += 4) {
        int s0 = csr[j], s1 = csr[j + 1], s2 = csr[j + 2], s3 = csr[j + 3];
        float v0 = feat[(size_t)s0 * 64 + f];
        float v1 = feat[(size_t)s1 * 64 + f];
        float v2 = feat[(size_t)s2 * 64 + f];
        float v3 = feat[(size_t)s3 * 64 + f];
        acc += v0; acc += v1; acc += v2; acc += v3;
    }
    for (; j < end; ++j) acc += feat[(size_t)csr[j] * 64 + f];
    A[(size_t)wid * 64 + f] = acc * inv[wid];
}

// ---- Node transform: C[n][:] = agg[n] @ Wl^T + b + X[n] @ Wr^T -------------
// Stages [agg | X] tile (K=128) + transposed weights in LDS; f32 VALU GEMM.
__global__ __launch_bounds__(256) void k_gemm(const float* __restrict__ Aagg,
                                              const float* __restrict__ X,
                                              const float* __restrict__ Wl,
                                              const float* __restrict__ Wr,
                                              const float* __restrict__ bias,
                                              float* __restrict__ C) {
    __shared__ float As[64][132];    // +4 pad
    __shared__ float Ws[128][64];    // Ws[k][fo] transposed
    const int t = threadIdx.x;
    const int n0 = blockIdx.x * 64;

    for (int e = t; e < 4096; e += 256) {
        int fo = e >> 6, k = e & 63;
        Ws[k][fo] = Wl[e];
        Ws[64 + k][fo] = Wr[e];
    }
    for (int v = t; v < 2048; v += 256) {
        int row = v >> 5;
        int col = (v & 31) << 2;
        int n = n0 + row;
        float4 val = make_float4(0.f, 0.f, 0.f, 0.f);
        if (n < NN) {
            val = (col < 64) ? *(const float4*)(Aagg + (size_t)n * 64 + col)
                             : *(const float4*)(X + (size_t)n * 64 + (col - 64));
        }
        *(float4*)(&As[row][col]) = val;
    }
    __syncthreads();

    const int tx = t & 15;
    const int ty = t >> 4;
    float acc[4][4] = {};
    #pragma unroll 2
    for (int k = 0; k < 128; k += 4) {
        float a[4][4], w[4][4];
        #pragma unroll
        for (int i = 0; i < 4; ++i)
            *(float4*)a[i] = *(const float4*)(&As[ty * 4 + i][k]);
        #pragma unroll
        for (int kk = 0; kk < 4; ++kk)
            *(float4*)w[kk] = *(const float4*)(&Ws[k + kk][tx * 4]);
        #pragma unroll
        for (int i = 0; i < 4; ++i)
            #pragma unroll
            for (int kk = 0; kk < 4; ++kk)
                #pragma unroll
                for (int j = 0; j < 4; ++j)
                    acc[i][j] = fmaf(a[i][kk], w[kk][j], acc[i][j]);
    }

    float4 bv = *(const float4*)(bias + tx * 4);
    #pragma unroll
    for (int i = 0; i < 4; ++i) {
        int n = n0 + ty * 4 + i;
        if (n < NN) {
            float4 o;
            o.x = acc[i][0] + bv.x;
            o.y = acc[i][1] + bv.y;
            o.z = acc[i][2] + bv.z;
            o.w = acc[i][3] + bv.w;
            *(float4*)(C + (size_t)n * 64 + tx * 4) = o;
        }
    }
}

// ---- host ------------------------------------------------------------------

extern "C" void kernel_launch(void* const* d_in, const int* in_sizes, int n_in,
                              void* d_out, int out_size, void* d_ws, size_t ws_size,
                              hipStream_t stream) {
    const float* x   = (const float*)d_in[0];
    const int*   ei  = (const int*)d_in[1];
    const int*   src = ei;
    const int*   dst = ei + NE;
    const float* Wl1 = (const float*)d_in[2];
    const float* b1  = (const float*)d_in[3];
    const float* Wr1 = (const float*)d_in[4];
    const float* Wl2 = (const float*)d_in[5];
    const float* b2  = (const float*)d_in[6];
    const float* Wr2 = (const float*)d_in[7];
    float* out = (float*)d_out;

    char* ws = (char*)d_ws;
    size_t off = 0;
    auto alloc = [&](size_t bytes) {
        void* p = ws + off;
        off = (off + bytes + 255) & ~(size_t)255;
        return p;
    };
    float*    A      = (float*)alloc(sizeof(float) * (size_t)NN * 64);      // 25.6 MB
    unsigned* binned = (unsigned*)alloc(sizeof(unsigned) * NB * BCAP);      // 7.2 MB
    int2*     noff   = (int2*)alloc(sizeof(int2) * NN);                     // 0.8 MB
    float*    inv    = (float*)alloc(sizeof(float) * NN);                   // 0.4 MB
    int*      gcur   = (int*)alloc(sizeof(int) * NB);

    // CSR build (no global scatter-atomics; reused by both layers)
    k_init<<<1, 256, 0, stream>>>(gcur);
    k_bin <<<BIN_BLKS, 256, 0, stream>>>(src, dst, gcur, binned);
    k_csr <<<NB, 256, 0, stream>>>(gcur, binned, noff, inv);

    // layer 1
    k_agg <<<((size_t)NN * 64 + 255) / 256, 256, 0, stream>>>(x, noff, binned, inv, A);
    k_gemm<<<(NN + 63) / 64, 256, 0, stream>>>(A, x, Wl1, Wr1, b1, out);

    // layer 2
    k_agg <<<((size_t)NN * 64 + 255) / 256, 256, 0, stream>>>(out, noff, binned, inv, A);
    k_gemm<<<(NN + 63) / 64, 256, 0, stream>>>(A, out, Wl2, Wr2, b2, out);
}

// Round 4
// 216.154 us; speedup vs baseline: 2.8308x; 1.3948x over previous
//
#include <hip/hip_runtime.h>
#include <hip/hip_bf16.h>

#define NN 100000
#define NE 1600000
#define NB 196            // dst-range buckets of 512 nodes
#define BCAP 9216         // padded bucket capacity (mean 8192, sd ~90 -> +11 sigma)
#define BIN_CHUNK 8192
#define BIN_BLKS ((NE + BIN_CHUNK - 1) / BIN_CHUNK)   // 196

typedef __attribute__((ext_vector_type(8))) short bf16x8;
typedef __attribute__((ext_vector_type(4))) float f32x4;

__device__ inline unsigned short f2bf(float f) {
    union { __hip_bfloat16 h; unsigned short u; } c;
    c.h = __float2bfloat16(f);
    return c.u;
}

// ---- bucket cursors init ---------------------------------------------------
__global__ void k_init(int* __restrict__ gcur) {
    int t = threadIdx.x;
    if (t < NB) gcur[t] = t * BCAP;
}

// ---- weights -> bf16, Wcat[fo][0:64]=Wl[fo][:], [64:128]=Wr[fo][:] ---------
__global__ void k_wcvt(const float* __restrict__ Wl1, const float* __restrict__ Wr1,
                       const float* __restrict__ Wl2, const float* __restrict__ Wr2,
                       unsigned short* __restrict__ Wc1, unsigned short* __restrict__ Wc2) {
    int e = blockIdx.x * 256 + threadIdx.x;
    if (e < 4096) {
        int fo = e >> 6, k = e & 63;
        Wc1[fo * 128 + k]      = f2bf(Wl1[e]);
        Wc1[fo * 128 + 64 + k] = f2bf(Wr1[e]);
        Wc2[fo * 128 + k]      = f2bf(Wl2[e]);
        Wc2[fo * 128 + 64 + k] = f2bf(Wr2[e]);
    }
}

// ---- bin edges by dst>>9 into padded bucket regions ------------------------
__global__ __launch_bounds__(256) void k_bin(const int* __restrict__ src,
                                             const int* __restrict__ dst,
                                             int* __restrict__ gcur,
                                             unsigned* __restrict__ binned) {
    __shared__ int hist[NB];
    __shared__ int base[NB];
    __shared__ int lcur[NB];
    const int t = threadIdx.x;
    const int e0 = blockIdx.x * BIN_CHUNK;
    const int n = min(BIN_CHUNK, NE - e0);
    for (int i = t; i < NB; i += 256) { hist[i] = 0; lcur[i] = 0; }
    __syncthreads();
    for (int i = t; i < n; i += 256)
        atomicAdd(&hist[dst[e0 + i] >> 9], 1);
    __syncthreads();
    for (int i = t; i < NB; i += 256) {
        int h = hist[i];
        base[i] = h ? atomicAdd(&gcur[i], h) : 0;
    }
    __syncthreads();
    for (int i = t; i < n; i += 256) {
        int d = dst[e0 + i];
        int s = src[e0 + i];
        int b = d >> 9;
        int p = base[b] + atomicAdd(&lcur[b], 1);
        binned[p] = ((unsigned)(d & 511) << 17) | (unsigned)s;
    }
}

// ---- per-bucket CSR finalize -----------------------------------------------
__global__ __launch_bounds__(256) void k_csr(const int* __restrict__ gcur,
                                             unsigned* __restrict__ binned,
                                             int2* __restrict__ noff,
                                             float* __restrict__ inv) {
    __shared__ unsigned buf[BCAP];
    __shared__ int h[512];
    __shared__ int off[512];
    __shared__ int lcur[512];
    __shared__ int s[256];
    const int b = blockIdx.x;
    const int t = threadIdx.x;
    const int base = b * BCAP;
    const int cnt = min(gcur[b] - base, BCAP);
    for (int i = t; i < 512; i += 256) h[i] = 0;
    __syncthreads();
    for (int i = t; i < cnt; i += 256) {
        unsigned v = binned[base + i];
        buf[i] = v;
        atomicAdd(&h[v >> 17], 1);
    }
    __syncthreads();
    int a0 = h[2 * t], a1 = h[2 * t + 1];
    s[t] = a0 + a1;
    __syncthreads();
    #pragma unroll
    for (int o = 1; o < 256; o <<= 1) {
        int u = (t >= o) ? s[t - o] : 0;
        __syncthreads();
        s[t] += u;
        __syncthreads();
    }
    int ex = s[t] - (a0 + a1);
    off[2 * t] = ex;          lcur[2 * t] = ex;
    off[2 * t + 1] = ex + a0; lcur[2 * t + 1] = ex + a0;
    __syncthreads();
    for (int i = t; i < cnt; i += 256) {
        unsigned v = buf[i];
        int dl = v >> 17;
        int p = atomicAdd(&lcur[dl], 1);
        binned[base + p] = v & 0x1FFFFu;
    }
    #pragma unroll
    for (int q = 0; q < 2; ++q) {
        int l = 2 * t + q;
        int node = b * 512 + l;
        if (node < NN) {
            int st = base + off[l];
            noff[node] = make_int2(st, st + h[l]);
            inv[node] = 1.0f / fmaxf((float)h[l], 1.0f);
        }
    }
}

// ---- Aggregation: wave per node; 4 edge-slots x 16 feature-quads -----------
// lane = q*16 + p: slot q handles edges beg+q, beg+q+4, ...; lane loads
// float4 of features [4p, 4p+4). Cross-slot reduce via 2 shfl_xor steps.
// Output A is bf16 [NN][64].
__global__ void k_agg(const float* __restrict__ feat, const int2* __restrict__ noff,
                      const unsigned* __restrict__ csr, const float* __restrict__ inv,
                      unsigned short* __restrict__ A) {
    int wid = (blockIdx.x * blockDim.x + threadIdx.x) >> 6;
    int lane = threadIdx.x & 63;
    int q = lane >> 4;
    int p = lane & 15;
    if (wid >= NN) return;
    int2 oe = noff[wid];
    int beg = oe.x, end = oe.y;
    float ax0 = 0.f, ay0 = 0.f, az0 = 0.f, aw0 = 0.f;
    float ax1 = 0.f, ay1 = 0.f, az1 = 0.f, aw1 = 0.f;
    int j = beg + q;
    for (; j + 4 < end; j += 8) {
        unsigned s0 = csr[j];
        unsigned s1 = csr[j + 4];
        float4 v0 = ((const float4*)(feat + (size_t)s0 * 64))[p];
        float4 v1 = ((const float4*)(feat + (size_t)s1 * 64))[p];
        ax0 += v0.x; ay0 += v0.y; az0 += v0.z; aw0 += v0.w;
        ax1 += v1.x; ay1 += v1.y; az1 += v1.z; aw1 += v1.w;
    }
    if (j < end) {
        unsigned s0 = csr[j];
        float4 v0 = ((const float4*)(feat + (size_t)s0 * 64))[p];
        ax0 += v0.x; ay0 += v0.y; az0 += v0.z; aw0 += v0.w;
    }
    float rx = ax0 + ax1, ry = ay0 + ay1, rz = az0 + az1, rw = aw0 + aw1;
    rx += __shfl_xor(rx, 16); rx += __shfl_xor(rx, 32);
    ry += __shfl_xor(ry, 16); ry += __shfl_xor(ry, 32);
    rz += __shfl_xor(rz, 16); rz += __shfl_xor(rz, 32);
    rw += __shfl_xor(rw, 16); rw += __shfl_xor(rw, 32);
    if (q == 0) {
        float iv = inv[wid];
        ushort4 u;
        u.x = f2bf(rx * iv); u.y = f2bf(ry * iv);
        u.z = f2bf(rz * iv); u.w = f2bf(rw * iv);
        *(ushort4*)(A + (size_t)wid * 64 + p * 4) = u;
    }
}

// ---- Node transform via bf16 MFMA, LDS-free --------------------------------
// C[n][fo] = sum_k [Abf(n)|bf16(X(n))][k] * Wcat[fo][k] + bias[fo]
// 4 waves/block; wave w owns node strip n0+w*16..+15, all 64 fo, K=128.
__global__ __launch_bounds__(256) void k_gemm(const unsigned short* __restrict__ Aagg,
                                              const float* __restrict__ X,
                                              const unsigned short* __restrict__ Wc,
                                              const float* __restrict__ bias,
                                              float* __restrict__ C) {
    const int t = threadIdx.x;
    const int w = t >> 6;
    const int l = t & 63;
    const int cn = l & 15;        // A-row / B-col / C-col selector
    const int ks = l >> 4;        // k-subgroup 0..3
    const int n0 = blockIdx.x * 64 + w * 16;

    int arow = n0 + cn;
    int aclamp = (arow < NN) ? arow : 0;

    f32x4 acc0 = {0.f, 0.f, 0.f, 0.f};
    f32x4 acc1 = {0.f, 0.f, 0.f, 0.f};
    f32x4 acc2 = {0.f, 0.f, 0.f, 0.f};
    f32x4 acc3 = {0.f, 0.f, 0.f, 0.f};

    #pragma unroll
    for (int kb = 0; kb < 4; ++kb) {
        bf16x8 a;
        if (kb < 2) {
            a = *(const bf16x8*)(Aagg + (size_t)aclamp * 64 + kb * 32 + ks * 8);
        } else {
            const float* xp = X + (size_t)aclamp * 64 + (kb - 2) * 32 + ks * 8;
            f32x4 x0 = *(const f32x4*)xp;
            f32x4 x1 = *(const f32x4*)(xp + 4);
            union { bf16x8 v; unsigned short u[8]; } cu;
            cu.u[0] = f2bf(x0.x); cu.u[1] = f2bf(x0.y);
            cu.u[2] = f2bf(x0.z); cu.u[3] = f2bf(x0.w);
            cu.u[4] = f2bf(x1.x); cu.u[5] = f2bf(x1.y);
            cu.u[6] = f2bf(x1.z); cu.u[7] = f2bf(x1.w);
            a = cu.v;
        }
        const unsigned short* wb = Wc + cn * 128 + kb * 32 + ks * 8;
        bf16x8 b0 = *(const bf16x8*)(wb);
        bf16x8 b1 = *(const bf16x8*)(wb + 16 * 128);
        bf16x8 b2 = *(const bf16x8*)(wb + 32 * 128);
        bf16x8 b3 = *(const bf16x8*)(wb + 48 * 128);
        acc0 = __builtin_amdgcn_mfma_f32_16x16x32_bf16(a, b0, acc0, 0, 0, 0);
        acc1 = __builtin_amdgcn_mfma_f32_16x16x32_bf16(a, b1, acc1, 0, 0, 0);
        acc2 = __builtin_amdgcn_mfma_f32_16x16x32_bf16(a, b2, acc2, 0, 0, 0);
        acc3 = __builtin_amdgcn_mfma_f32_16x16x32_bf16(a, b3, acc3, 0, 0, 0);
    }

    // C/D layout: col = lane&15, row = (lane>>4)*4 + r
    #pragma unroll
    for (int f = 0; f < 4; ++f) {
        f32x4 av = (f == 0) ? acc0 : (f == 1) ? acc1 : (f == 2) ? acc2 : acc3;
        float bv = bias[f * 16 + cn];
        #pragma unroll
        for (int r = 0; r < 4; ++r) {
            int node = n0 + ks * 4 + r;
            if (node < NN)
                C[(size_t)node * 64 + f * 16 + cn] = av[r] + bv;
        }
    }
}

// ---- host ------------------------------------------------------------------

extern "C" void kernel_launch(void* const* d_in, const int* in_sizes, int n_in,
                              void* d_out, int out_size, void* d_ws, size_t ws_size,
                              hipStream_t stream) {
    const float* x   = (const float*)d_in[0];
    const int*   ei  = (const int*)d_in[1];
    const int*   src = ei;
    const int*   dst = ei + NE;
    const float* Wl1 = (const float*)d_in[2];
    const float* b1  = (const float*)d_in[3];
    const float* Wr1 = (const float*)d_in[4];
    const float* Wl2 = (const float*)d_in[5];
    const float* b2  = (const float*)d_in[6];
    const float* Wr2 = (const float*)d_in[7];
    float* out = (float*)d_out;

    char* ws = (char*)d_ws;
    size_t off = 0;
    auto alloc = [&](size_t bytes) {
        void* p = ws + off;
        off = (off + bytes + 255) & ~(size_t)255;
        return p;
    };
    unsigned short* A      = (unsigned short*)alloc(2 * (size_t)NN * 64);   // 12.8 MB
    unsigned*       binned = (unsigned*)alloc(sizeof(unsigned) * NB * BCAP);// 7.2 MB
    int2*           noff   = (int2*)alloc(sizeof(int2) * NN);
    float*          inv    = (float*)alloc(sizeof(float) * NN);
    int*            gcur   = (int*)alloc(sizeof(int) * NB);
    unsigned short* Wc1    = (unsigned short*)alloc(2 * 64 * 128);
    unsigned short* Wc2    = (unsigned short*)alloc(2 * 64 * 128);

    // CSR build + weight convert (reused by both layers)
    k_init<<<1, 256, 0, stream>>>(gcur);
    k_wcvt<<<16, 256, 0, stream>>>(Wl1, Wr1, Wl2, Wr2, Wc1, Wc2);
    k_bin <<<BIN_BLKS, 256, 0, stream>>>(src, dst, gcur, binned);
    k_csr <<<NB, 256, 0, stream>>>(gcur, binned, noff, inv);

    // layer 1
    k_agg <<<((size_t)NN * 64 + 255) / 256, 256, 0, stream>>>(x, noff, binned, inv, A);
    k_gemm<<<(NN + 63) / 64, 256, 0, stream>>>(A, x, Wc1, b1, out);

    // layer 2
    k_agg <<<((size_t)NN * 64 + 255) / 256, 256, 0, stream>>>(out, noff, binned, inv, A);
    k_gemm<<<(NN + 63) / 64, 256, 0, stream>>>(A, out, Wc2, b2, out);
}

// Round 5
// 191.290 us; speedup vs baseline: 3.1988x; 1.1300x over previous
//
#include <hip/hip_runtime.h>
#include <hip/hip_bf16.h>

#define NN 100000
#define NE 1600000
#define NB 196            // dst-range buckets of 512 nodes
#define BCAP 9216         // padded bucket capacity (mean 8192, sd ~90 -> +11 sigma)
#define BIN_CHUNK 8192
#define BIN_BLKS ((NE + BIN_CHUNK - 1) / BIN_CHUNK)   // 196

typedef __attribute__((ext_vector_type(8))) short bf16x8;
typedef __attribute__((ext_vector_type(4))) float f32x4;

__device__ inline unsigned short f2bf(float f) {
    union { __hip_bfloat16 h; unsigned short u; } c;
    c.h = __float2bfloat16(f);
    return c.u;
}

// ---- bucket cursors init ---------------------------------------------------
__global__ void k_init(int* __restrict__ gcur) {
    int t = threadIdx.x;
    if (t < NB) gcur[t] = t * BCAP;
}

// ---- weights -> bf16, Wcat[fo][0:64]=Wl[fo][:], [64:128]=Wr[fo][:] ---------
__global__ void k_wcvt(const float* __restrict__ Wl1, const float* __restrict__ Wr1,
                       const float* __restrict__ Wl2, const float* __restrict__ Wr2,
                       unsigned short* __restrict__ Wc1, unsigned short* __restrict__ Wc2) {
    int e = blockIdx.x * 256 + threadIdx.x;
    if (e < 4096) {
        int fo = e >> 6, k = e & 63;
        Wc1[fo * 128 + k]      = f2bf(Wl1[e]);
        Wc1[fo * 128 + 64 + k] = f2bf(Wr1[e]);
        Wc2[fo * 128 + k]      = f2bf(Wl2[e]);
        Wc2[fo * 128 + 64 + k] = f2bf(Wr2[e]);
    }
}

// ---- x (f32) -> bf16 table --------------------------------------------------
__global__ __launch_bounds__(256) void k_xcvt(const float* __restrict__ x,
                                              unsigned short* __restrict__ xb) {
    int i = blockIdx.x * 256 + threadIdx.x;     // 8 elements per thread
    if (i >= NN * 64 / 8) return;
    const float4* p = (const float4*)(x + (size_t)i * 8);
    float4 v0 = p[0], v1 = p[1];
    union { bf16x8 v; unsigned short u[8]; } c;
    c.u[0] = f2bf(v0.x); c.u[1] = f2bf(v0.y); c.u[2] = f2bf(v0.z); c.u[3] = f2bf(v0.w);
    c.u[4] = f2bf(v1.x); c.u[5] = f2bf(v1.y); c.u[6] = f2bf(v1.z); c.u[7] = f2bf(v1.w);
    *(bf16x8*)(xb + (size_t)i * 8) = c.v;
}

// ---- bin edges by dst>>9 into padded bucket regions ------------------------
__global__ __launch_bounds__(256) void k_bin(const int* __restrict__ src,
                                             const int* __restrict__ dst,
                                             int* __restrict__ gcur,
                                             unsigned* __restrict__ binned) {
    __shared__ int hist[NB];
    __shared__ int base[NB];
    __shared__ int lcur[NB];
    const int t = threadIdx.x;
    const int e0 = blockIdx.x * BIN_CHUNK;
    const int n = min(BIN_CHUNK, NE - e0);
    for (int i = t; i < NB; i += 256) { hist[i] = 0; lcur[i] = 0; }
    __syncthreads();
    for (int i = t; i < n; i += 256)
        atomicAdd(&hist[dst[e0 + i] >> 9], 1);
    __syncthreads();
    for (int i = t; i < NB; i += 256) {
        int h = hist[i];
        base[i] = h ? atomicAdd(&gcur[i], h) : 0;
    }
    __syncthreads();
    for (int i = t; i < n; i += 256) {
        int d = dst[e0 + i];
        int s = src[e0 + i];
        int b = d >> 9;
        int p = base[b] + atomicAdd(&lcur[b], 1);
        binned[p] = ((unsigned)(d & 511) << 17) | (unsigned)s;
    }
}

// ---- per-bucket CSR finalize -----------------------------------------------
__global__ __launch_bounds__(256) void k_csr(const int* __restrict__ gcur,
                                             unsigned* __restrict__ binned,
                                             int2* __restrict__ noff,
                                             float* __restrict__ inv) {
    __shared__ unsigned buf[BCAP];
    __shared__ int h[512];
    __shared__ int off[512];
    __shared__ int lcur[512];
    __shared__ int s[256];
    const int b = blockIdx.x;
    const int t = threadIdx.x;
    const int base = b * BCAP;
    const int cnt = min(gcur[b] - base, BCAP);
    for (int i = t; i < 512; i += 256) h[i] = 0;
    __syncthreads();
    for (int i = t; i < cnt; i += 256) {
        unsigned v = binned[base + i];
        buf[i] = v;
        atomicAdd(&h[v >> 17], 1);
    }
    __syncthreads();
    int a0 = h[2 * t], a1 = h[2 * t + 1];
    s[t] = a0 + a1;
    __syncthreads();
    #pragma unroll
    for (int o = 1; o < 256; o <<= 1) {
        int u = (t >= o) ? s[t - o] : 0;
        __syncthreads();
        s[t] += u;
        __syncthreads();
    }
    int ex = s[t] - (a0 + a1);
    off[2 * t] = ex;          lcur[2 * t] = ex;
    off[2 * t + 1] = ex + a0; lcur[2 * t + 1] = ex + a0;
    __syncthreads();
    for (int i = t; i < cnt; i += 256) {
        unsigned v = buf[i];
        int dl = v >> 17;
        int p = atomicAdd(&lcur[dl], 1);
        binned[base + p] = v & 0x1FFFFu;
    }
    #pragma unroll
    for (int q = 0; q < 2; ++q) {
        int l = 2 * t + q;
        int node = b * 512 + l;
        if (node < NN) {
            int st = base + off[l];
            noff[node] = make_int2(st, st + h[l]);
            inv[node] = 1.0f / fmaxf((float)h[l], 1.0f);
        }
    }
}

// ---- Aggregation over bf16 features: wave/node, 8 slots x 8 feature-octets -
// lane = q*8+p: slot q handles edges beg+q, beg+q+8, ...; lane gathers 16 B
// (8 bf16 feats [8p,8p+8)). 8-lane groups read a full 128 B row. Reduce over
// q via 3 shfl_xor. Output A bf16 [NN][64].
__global__ void k_agg(const unsigned short* __restrict__ feat,
                      const int2* __restrict__ noff,
                      const unsigned* __restrict__ csr, const float* __restrict__ inv,
                      unsigned short* __restrict__ A) {
    int wid = (blockIdx.x * blockDim.x + threadIdx.x) >> 6;
    int lane = threadIdx.x & 63;
    int q = lane >> 3;
    int p = lane & 7;
    if (wid >= NN) return;
    int2 oe = noff[wid];
    int beg = oe.x, end = oe.y;
    float a[8] = {0.f, 0.f, 0.f, 0.f, 0.f, 0.f, 0.f, 0.f};

    #define UNPK(uu, k)                                        \
        a[2*(k)]   += __uint_as_float((uu) << 16);             \
        a[2*(k)+1] += __uint_as_float((uu) & 0xffff0000u);

    int j = beg + q;
    for (; j + 8 < end; j += 16) {
        uint4 u = *(const uint4*)(feat + (size_t)csr[j] * 64 + p * 8);
        uint4 v = *(const uint4*)(feat + (size_t)csr[j + 8] * 64 + p * 8);
        UNPK(u.x, 0) UNPK(u.y, 1) UNPK(u.z, 2) UNPK(u.w, 3)
        UNPK(v.x, 0) UNPK(v.y, 1) UNPK(v.z, 2) UNPK(v.w, 3)
    }
    if (j < end) {
        uint4 u = *(const uint4*)(feat + (size_t)csr[j] * 64 + p * 8);
        UNPK(u.x, 0) UNPK(u.y, 1) UNPK(u.z, 2) UNPK(u.w, 3)
    }
    #undef UNPK

    #pragma unroll
    for (int e = 0; e < 8; ++e) {
        a[e] += __shfl_xor(a[e], 8);
        a[e] += __shfl_xor(a[e], 16);
        a[e] += __shfl_xor(a[e], 32);
    }
    if (q == 0) {
        float iv = inv[wid];
        union { bf16x8 v; unsigned short u[8]; } c;
        #pragma unroll
        for (int e = 0; e < 8; ++e) c.u[e] = f2bf(a[e] * iv);
        *(bf16x8*)(A + (size_t)wid * 64 + p * 8) = c.v;
    }
}

// ---- Node transform via bf16 MFMA, LDS-free --------------------------------
// C[n][fo] = sum_k [Ab(n)|Xb(n)][k] * Wcat[fo][k] + bias[fo]
// 4 waves/block; wave w owns node strip n0+w*16..+15, all 64 fo, K=128.
// Output: f32 to Cf (if Cb==0) else bf16 to Cb.
__global__ __launch_bounds__(256) void k_gemm(const unsigned short* __restrict__ Ab,
                                              const unsigned short* __restrict__ Xb,
                                              const unsigned short* __restrict__ Wc,
                                              const float* __restrict__ bias,
                                              float* __restrict__ Cf,
                                              unsigned short* __restrict__ Cb) {
    const int t = threadIdx.x;
    const int w = t >> 6;
    const int l = t & 63;
    const int cn = l & 15;        // A-row / B-col / C-col selector
    const int ks = l >> 4;        // k-subgroup 0..3
    const int n0 = blockIdx.x * 64 + w * 16;

    int arow = n0 + cn;
    int aclamp = (arow < NN) ? arow : 0;

    f32x4 acc0 = {0.f, 0.f, 0.f, 0.f};
    f32x4 acc1 = {0.f, 0.f, 0.f, 0.f};
    f32x4 acc2 = {0.f, 0.f, 0.f, 0.f};
    f32x4 acc3 = {0.f, 0.f, 0.f, 0.f};

    #pragma unroll
    for (int kb = 0; kb < 4; ++kb) {
        const unsigned short* ap = (kb < 2)
            ? (Ab + (size_t)aclamp * 64 + kb * 32 + ks * 8)
            : (Xb + (size_t)aclamp * 64 + (kb - 2) * 32 + ks * 8);
        bf16x8 aa = *(const bf16x8*)ap;
        const unsigned short* wb = Wc + cn * 128 + kb * 32 + ks * 8;
        bf16x8 b0 = *(const bf16x8*)(wb);
        bf16x8 b1 = *(const bf16x8*)(wb + 16 * 128);
        bf16x8 b2 = *(const bf16x8*)(wb + 32 * 128);
        bf16x8 b3 = *(const bf16x8*)(wb + 48 * 128);
        acc0 = __builtin_amdgcn_mfma_f32_16x16x32_bf16(aa, b0, acc0, 0, 0, 0);
        acc1 = __builtin_amdgcn_mfma_f32_16x16x32_bf16(aa, b1, acc1, 0, 0, 0);
        acc2 = __builtin_amdgcn_mfma_f32_16x16x32_bf16(aa, b2, acc2, 0, 0, 0);
        acc3 = __builtin_amdgcn_mfma_f32_16x16x32_bf16(aa, b3, acc3, 0, 0, 0);
    }

    // C/D layout: col = lane&15, row = (lane>>4)*4 + r
    #pragma unroll
    for (int f = 0; f < 4; ++f) {
        f32x4 av = (f == 0) ? acc0 : (f == 1) ? acc1 : (f == 2) ? acc2 : acc3;
        float bv = bias[f * 16 + cn];
        #pragma unroll
        for (int r = 0; r < 4; ++r) {
            int node = n0 + ks * 4 + r;
            if (node < NN) {
                float val = av[r] + bv;
                if (Cb) Cb[(size_t)node * 64 + f * 16 + cn] = f2bf(val);
                else    Cf[(size_t)node * 64 + f * 16 + cn] = val;
            }
        }
    }
}

// ---- host ------------------------------------------------------------------

extern "C" void kernel_launch(void* const* d_in, const int* in_sizes, int n_in,
                              void* d_out, int out_size, void* d_ws, size_t ws_size,
                              hipStream_t stream) {
    const float* x   = (const float*)d_in[0];
    const int*   ei  = (const int*)d_in[1];
    const int*   src = ei;
    const int*   dst = ei + NE;
    const float* Wl1 = (const float*)d_in[2];
    const float* b1  = (const float*)d_in[3];
    const float* Wr1 = (const float*)d_in[4];
    const float* Wl2 = (const float*)d_in[5];
    const float* b2  = (const float*)d_in[6];
    const float* Wr2 = (const float*)d_in[7];
    float* out = (float*)d_out;

    char* ws = (char*)d_ws;
    size_t off = 0;
    auto alloc = [&](size_t bytes) {
        void* p = ws + off;
        off = (off + bytes + 255) & ~(size_t)255;
        return p;
    };
    unsigned short* A      = (unsigned short*)alloc(2 * (size_t)NN * 64);   // 12.8 MB
    unsigned short* xb     = (unsigned short*)alloc(2 * (size_t)NN * 64);   // 12.8 MB
    unsigned short* h1b    = (unsigned short*)alloc(2 * (size_t)NN * 64);   // 12.8 MB
    unsigned*       binned = (unsigned*)alloc(sizeof(unsigned) * NB * BCAP);// 7.2 MB
    int2*           noff   = (int2*)alloc(sizeof(int2) * NN);
    float*          inv    = (float*)alloc(sizeof(float) * NN);
    int*            gcur   = (int*)alloc(sizeof(int) * NB);
    unsigned short* Wc1    = (unsigned short*)alloc(2 * 64 * 128);
    unsigned short* Wc2    = (unsigned short*)alloc(2 * 64 * 128);

    // one-time prep (reused by both layers)
    k_init<<<1, 256, 0, stream>>>(gcur);
    k_wcvt<<<16, 256, 0, stream>>>(Wl1, Wr1, Wl2, Wr2, Wc1, Wc2);
    k_xcvt<<<(NN * 64 / 8 + 255) / 256, 256, 0, stream>>>(x, xb);
    k_bin <<<BIN_BLKS, 256, 0, stream>>>(src, dst, gcur, binned);
    k_csr <<<NB, 256, 0, stream>>>(gcur, binned, noff, inv);

    // layer 1: h1b (bf16) = [agg(xb) | xb] @ Wc1^T + b1
    k_agg <<<((size_t)NN * 64 + 255) / 256, 256, 0, stream>>>(xb, noff, binned, inv, A);
    k_gemm<<<(NN + 63) / 64, 256, 0, stream>>>(A, xb, Wc1, b1, (float*)nullptr, h1b);

    // layer 2: out (f32) = [agg(h1b) | h1b] @ Wc2^T + b2
    k_agg <<<((size_t)NN * 64 + 255) / 256, 256, 0, stream>>>(h1b, noff, binned, inv, A);
    k_gemm<<<(NN + 63) / 64, 256, 0, stream>>>(A, h1b, Wc2, b2, out, (unsigned short*)nullptr);
}